// Round 3
// baseline (96.799 us; speedup 1.0000x reference)
//
#include <hip/hip_runtime.h>
#include <hip/hip_bf16.h>

// out[i][j] = (j < pos[i]) ? images[i][j] : 0
// N = 16384 rows, L = 4096 cols, fp32.
// One thread handles ITERS float4s via grid-stride; loads batched before
// stores for memory-level parallelism. Nontemporal hints: both streams are
// touch-once and far exceed L2 (32 MiB), so avoid cache allocation.
// Use a Clang ext_vector_type for the nontemporal builtins (HIP_vector_type
// is rejected by them).

typedef float f32x4 __attribute__((ext_vector_type(4)));

#define LOG2_C4 10   // log2(L/4) = log2(1024)
#define ITERS   8

__global__ __launch_bounds__(256)
void ControlFlowScanDecomposition_151564_46308337386065_kernel(
        const f32x4* __restrict__ img,
        const int*   __restrict__ pos,
        f32x4*       __restrict__ out,
        unsigned int n_vec4) {
    const unsigned int tid    = blockIdx.x * blockDim.x + threadIdx.x;
    const unsigned int stride = gridDim.x * blockDim.x;

    f32x4        v[ITERS];
    int          ps[ITERS];
    unsigned int ix[ITERS];

    // Phase 1: issue all loads (or zero-fill) — up to ITERS loads in flight.
    #pragma unroll
    for (int k = 0; k < ITERS; ++k) {
        const unsigned int idx = tid + (unsigned int)k * stride;
        ix[k] = idx;
        if (idx < n_vec4) {
            const unsigned int row = idx >> LOG2_C4;
            const int p  = pos[row];              // wave-uniform per iteration
            const int j0 = (int)((idx & ((1u << LOG2_C4) - 1u)) << 2);
            ps[k] = p;
            if (j0 >= p) {
                v[k] = (f32x4){0.f, 0.f, 0.f, 0.f};       // fully masked: no load
            } else {
                v[k] = __builtin_nontemporal_load(&img[idx]);
            }
        } else {
            ps[k] = 0;
            v[k] = (f32x4){0.f, 0.f, 0.f, 0.f};
        }
    }

    // Phase 2: mask straddling vectors and store.
    #pragma unroll
    for (int k = 0; k < ITERS; ++k) {
        const unsigned int idx = ix[k];
        if (idx >= n_vec4) continue;
        const int p  = ps[k];
        const int j0 = (int)((idx & ((1u << LOG2_C4) - 1u)) << 2);
        f32x4 w = v[k];
        if (j0 + 4 > p) {                          // straddle (or fully masked)
            w.x = (j0 + 0 < p) ? w.x : 0.f;
            w.y = (j0 + 1 < p) ? w.y : 0.f;
            w.z = (j0 + 2 < p) ? w.z : 0.f;
            w.w = (j0 + 3 < p) ? w.w : 0.f;
        }
        __builtin_nontemporal_store(w, &out[idx]);
    }
}

extern "C" void kernel_launch(void* const* d_in, const int* in_sizes, int n_in,
                              void* d_out, int out_size, void* d_ws, size_t ws_size,
                              hipStream_t stream) {
    const f32x4* img = (const f32x4*)d_in[0];
    const int*   pos = (const int*)d_in[1];
    f32x4*       out = (f32x4*)d_out;

    const unsigned int n_vec4 = (unsigned int)(out_size / 4); // 16,777,216
    const int block = 256;
    const int grid  = (int)((n_vec4 + block * ITERS - 1) / (block * ITERS)); // 8192

    ControlFlowScanDecomposition_151564_46308337386065_kernel
        <<<grid, block, 0, stream>>>(img, pos, out, n_vec4);
}

// Round 4
// 84.328 us; speedup vs baseline: 1.1479x; 1.1479x over previous
//
#include <hip/hip_runtime.h>
#include <hip/hip_bf16.h>

// out[i][j] = (j < pos[i]) ? images[i][j] : 0
// N = 16384 rows, L = 4096 cols, fp32.
//
// Each block owns 2 consecutive rows (2 * 4096 floats = 2048 float4 = 32 KB
// contiguous). 256 threads x 8 iterations; all 8 loads issued before stores
// (8 outstanding global_load_dwordx4 per lane). Row positions are
// block-uniform scalar loads. Exact grid (8192 blocks), no tail.
// No nontemporal hints (regressed in round 2/3 experiment).

#define C4_PER_ROW 1024   // float4 per row (L/4)
#define ITERS      8      // 2048 float4 per block / 256 threads

__global__ __launch_bounds__(256)
void ControlFlowScanDecomposition_151564_46308337386065_kernel(
        const float4* __restrict__ img,
        const int*    __restrict__ pos,
        float4*       __restrict__ out) {
    const int tid = threadIdx.x;
    const unsigned int base = blockIdx.x * 2048u;   // first float4 of this block
    const int row0 = blockIdx.x * 2;

    const int p0 = pos[row0];       // block-uniform -> scalar load
    const int p1 = pos[row0 + 1];

    float4 v[ITERS];

    // Phase 1: issue all loads (masked lanes zero-fill, no load issued).
    #pragma unroll
    for (int k = 0; k < ITERS; ++k) {
        const unsigned int off = (unsigned int)k * 256u + (unsigned int)tid; // 0..2047
        const int p  = (k < 4) ? p0 : p1;           // k compile-time -> folds
        const int j0 = (int)((off & (C4_PER_ROW - 1u)) << 2);
        if (j0 < p) {
            v[k] = img[base + off];
        } else {
            v[k] = make_float4(0.f, 0.f, 0.f, 0.f);
        }
    }

    // Phase 2: mask straddling vectors, store.
    #pragma unroll
    for (int k = 0; k < ITERS; ++k) {
        const unsigned int off = (unsigned int)k * 256u + (unsigned int)tid;
        const int p  = (k < 4) ? p0 : p1;
        const int j0 = (int)((off & (C4_PER_ROW - 1u)) << 2);
        float4 w = v[k];
        if (j0 + 4 > p) {                            // straddle or fully masked
            w.x = (j0 + 0 < p) ? w.x : 0.f;
            w.y = (j0 + 1 < p) ? w.y : 0.f;
            w.z = (j0 + 2 < p) ? w.z : 0.f;
            w.w = (j0 + 3 < p) ? w.w : 0.f;
        }
        out[base + off] = w;
    }
}

extern "C" void kernel_launch(void* const* d_in, const int* in_sizes, int n_in,
                              void* d_out, int out_size, void* d_ws, size_t ws_size,
                              hipStream_t stream) {
    const float4* img = (const float4*)d_in[0];
    const int*    pos = (const int*)d_in[1];
    float4*       out = (float4*)d_out;

    const int n_vec4 = out_size / 4;                // 16,777,216
    const int block  = 256;
    const int grid   = n_vec4 / (block * ITERS);    // 8192 (exact)

    ControlFlowScanDecomposition_151564_46308337386065_kernel
        <<<grid, block, 0, stream>>>(img, pos, out);
}

// Round 5
// 57.722 us; speedup vs baseline: 1.6770x; 1.4609x over previous
//
#include <hip/hip_runtime.h>
#include <hip/hip_bf16.h>

// out[i][j] = (j < pos[i]) ? images[i][j] : 0
// N = 16384 rows, L = 4096 cols, fp32.
//
// Round-4 structure (best known: 84.3 us): each block owns 2 consecutive rows
// (2048 float4 = 32 KB contiguous), 256 threads x 8 iters, all loads issued
// before stores. THIS ROUND'S single change: nontemporal STORES only
// (loads stay cached) — output is touch-once streaming, avoid L2
// write-allocate competing with the read stream.

typedef float f32x4 __attribute__((ext_vector_type(4)));

#define C4_PER_ROW 1024   // float4 per row (L/4)
#define ITERS      8      // 2048 float4 per block / 256 threads

__global__ __launch_bounds__(256)
void ControlFlowScanDecomposition_151564_46308337386065_kernel(
        const f32x4* __restrict__ img,
        const int*   __restrict__ pos,
        f32x4*       __restrict__ out) {
    const int tid = threadIdx.x;
    const unsigned int base = blockIdx.x * 2048u;   // first float4 of this block
    const int row0 = blockIdx.x * 2;

    const int p0 = pos[row0];       // block-uniform -> scalar load
    const int p1 = pos[row0 + 1];

    f32x4 v[ITERS];

    // Phase 1: issue all loads (masked lanes zero-fill, no load issued).
    #pragma unroll
    for (int k = 0; k < ITERS; ++k) {
        const unsigned int off = (unsigned int)k * 256u + (unsigned int)tid; // 0..2047
        const int p  = (k < 4) ? p0 : p1;           // k compile-time -> folds
        const int j0 = (int)((off & (C4_PER_ROW - 1u)) << 2);
        if (j0 < p) {
            v[k] = img[base + off];                 // cached load
        } else {
            v[k] = (f32x4){0.f, 0.f, 0.f, 0.f};
        }
    }

    // Phase 2: mask straddling vectors, nontemporal store.
    #pragma unroll
    for (int k = 0; k < ITERS; ++k) {
        const unsigned int off = (unsigned int)k * 256u + (unsigned int)tid;
        const int p  = (k < 4) ? p0 : p1;
        const int j0 = (int)((off & (C4_PER_ROW - 1u)) << 2);
        f32x4 w = v[k];
        if (j0 + 4 > p) {                            // straddle or fully masked
            w.x = (j0 + 0 < p) ? w.x : 0.f;
            w.y = (j0 + 1 < p) ? w.y : 0.f;
            w.z = (j0 + 2 < p) ? w.z : 0.f;
            w.w = (j0 + 3 < p) ? w.w : 0.f;
        }
        __builtin_nontemporal_store(w, &out[base + off]);
    }
}

extern "C" void kernel_launch(void* const* d_in, const int* in_sizes, int n_in,
                              void* d_out, int out_size, void* d_ws, size_t ws_size,
                              hipStream_t stream) {
    const f32x4* img = (const f32x4*)d_in[0];
    const int*   pos = (const int*)d_in[1];
    f32x4*       out = (f32x4*)d_out;

    const int n_vec4 = out_size / 4;                // 16,777,216
    const int block  = 256;
    const int grid   = n_vec4 / (block * ITERS);    // 8192 (exact)

    ControlFlowScanDecomposition_151564_46308337386065_kernel
        <<<grid, block, 0, stream>>>(img, pos, out);
}